// Round 1
// baseline (192.119 us; speedup 1.0000x reference)
//
#include <hip/hip_runtime.h>
#include <stdint.h>

#define Td 1024
#define Hd 1024
#define Id 1024
#define Ed 8
#define Kd 2
#define Ld 4
#define Rd 16
#define Nd 2048
#define TKd (Td*Kd)

typedef __bf16 bf16x8 __attribute__((ext_vector_type(8)));
typedef float f32x4 __attribute__((ext_vector_type(4)));

__device__ __forceinline__ ushort f2bf(float f) {
    uint32_t u = __builtin_bit_cast(uint32_t, f);
    return (ushort)((u + 0x7fffu + ((u >> 16) & 1u)) >> 16);
}
__device__ __forceinline__ float bf2f(ushort u) {
    uint32_t x = ((uint32_t)u) << 16;
    return __builtin_bit_cast(float, x);
}

// ---------------- convert hidden fp32 -> bf16 ----------------
__global__ void k_convert_x(const float* __restrict__ x, ushort* __restrict__ xb) {
    int i = blockIdx.x * blockDim.x + threadIdx.x;      // one float4 per thread
    float4 v = reinterpret_cast<const float4*>(x)[i];
    uint2 o;
    o.x = (uint)f2bf(v.x) | ((uint)f2bf(v.y) << 16);
    o.y = (uint)f2bf(v.z) | ((uint)f2bf(v.w) << 16);
    reinterpret_cast<uint2*>(xb)[i] = o;
}

// ---------------- route sort: bucket pairs by expert ----------------
__global__ void k_route(const int* __restrict__ topk_ids, int* __restrict__ sorted,
                        int* __restrict__ offs) {
    __shared__ int cnt[Ed];
    __shared__ int cur[Ed];
    int tid = threadIdx.x;            // 1024 threads, 2 pairs each
    if (tid < Ed) cnt[tid] = 0;
    __syncthreads();
    int e0 = topk_ids[tid];
    int e1 = topk_ids[tid + 1024];
    atomicAdd(&cnt[e0], 1);
    atomicAdd(&cnt[e1], 1);
    __syncthreads();
    if (tid == 0) {
        int s = 0;
        for (int e = 0; e < Ed; ++e) { offs[e] = s; cur[e] = s; s += cnt[e]; }
        offs[Ed] = s;
    }
    __syncthreads();
    int pos = atomicAdd(&cur[e0], 1);
    sorted[pos] = tid;
    pos = atomicAdd(&cur[e1], 1);
    sorted[pos] = tid + 1024;
}

// ---------------- grouped GEMM: C[p, n] = sum_k A[row(p), k] * B[e][n, k] ----------------
// A: bf16 rows of length 1024. B: fp32 [E][NCOLS][1024]. C: fp32 [TK][NCOLS].
template<int NCOLS, bool ROWDIV>
__global__ __launch_bounds__(256) void k_gemm(
    const ushort* __restrict__ Ab, const float* __restrict__ Bw,
    float* __restrict__ C, const int* __restrict__ sorted,
    const int* __restrict__ offs)
{
    const int e = blockIdx.z;
    const int mstart = offs[e] + blockIdx.y * 64;
    const int mend = offs[e + 1];
    if (mstart >= mend) return;
    const int n0 = blockIdx.x * 128;

    __shared__ ushort As[64][32];
    __shared__ ushort Bs[128][32];

    const int tid = threadIdx.x;
    const int lane = tid & 63;
    const int wave = tid >> 6;

    // A staging: thread -> (row, 8-wide k chunk)
    const int sarow = tid >> 2;
    const int sakc = (tid & 3) * 8;
    const ushort* aptr = nullptr;
    {
        int aIdx = mstart + sarow;
        if (aIdx < mend) {
            int p = sorted[aIdx];
            int ar = ROWDIV ? (p >> 1) : p;
            aptr = Ab + (size_t)ar * 1024 + sakc;
        }
    }
    // B staging: thread -> (row, 16-wide k chunk), convert fp32->bf16
    const int sbrow = tid >> 1;
    const int sbkc = (tid & 1) * 16;
    const float* bptr = Bw + ((size_t)e * NCOLS + n0 + sbrow) * 1024 + sbkc;

    f32x4 acc[4][2] = {};

    const int fr = lane & 15;
    const int fk = (lane >> 4) * 8;

    for (int k0 = 0; k0 < 1024; k0 += 32) {
        uint4 av = make_uint4(0u, 0u, 0u, 0u);
        if (aptr) av = *reinterpret_cast<const uint4*>(aptr + k0);
        *reinterpret_cast<uint4*>(&As[sarow][sakc]) = av;

        const float4* bp = reinterpret_cast<const float4*>(bptr + k0);
        float4 v0 = bp[0], v1 = bp[1], v2 = bp[2], v3 = bp[3];
        uint4 lo, hi;
        lo.x = (uint)f2bf(v0.x) | ((uint)f2bf(v0.y) << 16);
        lo.y = (uint)f2bf(v0.z) | ((uint)f2bf(v0.w) << 16);
        lo.z = (uint)f2bf(v1.x) | ((uint)f2bf(v1.y) << 16);
        lo.w = (uint)f2bf(v1.z) | ((uint)f2bf(v1.w) << 16);
        hi.x = (uint)f2bf(v2.x) | ((uint)f2bf(v2.y) << 16);
        hi.y = (uint)f2bf(v2.z) | ((uint)f2bf(v2.w) << 16);
        hi.z = (uint)f2bf(v3.x) | ((uint)f2bf(v3.y) << 16);
        hi.w = (uint)f2bf(v3.z) | ((uint)f2bf(v3.w) << 16);
        *reinterpret_cast<uint4*>(&Bs[sbrow][sbkc]) = lo;
        *reinterpret_cast<uint4*>(&Bs[sbrow][sbkc + 8]) = hi;

        __syncthreads();

        bf16x8 af[4], bfv[2];
        #pragma unroll
        for (int mi = 0; mi < 4; ++mi)
            af[mi] = *reinterpret_cast<const bf16x8*>(&As[mi * 16 + fr][fk]);
        #pragma unroll
        for (int ni = 0; ni < 2; ++ni)
            bfv[ni] = *reinterpret_cast<const bf16x8*>(&Bs[wave * 32 + ni * 16 + fr][fk]);
        #pragma unroll
        for (int mi = 0; mi < 4; ++mi) {
            #pragma unroll
            for (int ni = 0; ni < 2; ++ni)
                acc[mi][ni] = __builtin_amdgcn_mfma_f32_16x16x32_bf16(
                    af[mi], bfv[ni], acc[mi][ni], 0, 0, 0);
        }

        __syncthreads();
    }

    // epilogue: D layout col=lane&15, row=(lane>>4)*4+j
    const int colb = n0 + wave * 32 + fr;
    const int rb = (lane >> 4) * 4;
    #pragma unroll
    for (int mi = 0; mi < 4; ++mi) {
        #pragma unroll
        for (int j = 0; j < 4; ++j) {
            int sidx = mstart + mi * 16 + rb + j;
            if (sidx < mend) {
                int p = sorted[sidx];
                float* cr = C + (size_t)p * NCOLS + colb;
                cr[0]  = acc[mi][0][j];
                cr[16] = acc[mi][1][j];
            }
        }
    }
}

// ---------------- gate_up LoRA: cache1[p] += Bg[l,e] @ (Ag[l,e] @ x[t]) * scal ----------------
__global__ __launch_bounds__(256) void k_lora_gateup(
    const float* __restrict__ hid, const float* __restrict__ Ag,
    const float* __restrict__ Bg, const float* __restrict__ scal,
    const int* __restrict__ topk_ids, const int* __restrict__ lidx,
    float* __restrict__ cache1)
{
    const int p = blockIdx.x;
    const int t = p >> 1;
    const int e = topk_ids[p];
    const int l = lidx[t];
    const float s = scal[l];
    __shared__ float tmp[Rd];

    const int tid = threadIdx.x, lane = tid & 63, wave = tid >> 6;
    const int r = wave * 4 + (lane >> 4);
    const int hl = lane & 15;
    const float* arow = Ag + (((size_t)l * Ed + e) * Rd + r) * Hd;
    const float* xr = hid + (size_t)t * Hd;
    float a = 0.f;
    for (int h0 = hl * 4; h0 < Hd; h0 += 64) {
        float4 av = *reinterpret_cast<const float4*>(&arow[h0]);
        float4 xv = *reinterpret_cast<const float4*>(&xr[h0]);
        a += av.x * xv.x + av.y * xv.y + av.z * xv.z + av.w * xv.w;
    }
    a += __shfl_xor(a, 1); a += __shfl_xor(a, 2);
    a += __shfl_xor(a, 4); a += __shfl_xor(a, 8);
    if (hl == 0) tmp[r] = a;
    __syncthreads();

    float tl[Rd];
    #pragma unroll
    for (int q = 0; q < Rd; ++q) tl[q] = tmp[q];
    const float* Bbase = Bg + ((size_t)l * Ed + e) * Nd * Rd;
    for (int n = tid; n < Nd; n += 256) {
        const float4* br = reinterpret_cast<const float4*>(Bbase + (size_t)n * Rd);
        float4 b0 = br[0], b1 = br[1], b2 = br[2], b3 = br[3];
        float v = b0.x*tl[0] + b0.y*tl[1] + b0.z*tl[2] + b0.w*tl[3]
                + b1.x*tl[4] + b1.y*tl[5] + b1.z*tl[6] + b1.w*tl[7]
                + b2.x*tl[8] + b2.y*tl[9] + b2.z*tl[10] + b2.w*tl[11]
                + b3.x*tl[12] + b3.y*tl[13] + b3.z*tl[14] + b3.w*tl[15];
        cache1[(size_t)p * Nd + n] += v * s;
    }
}

// ---------------- silu_and_mul -> bf16 act ----------------
__global__ void k_silu(const float* __restrict__ c1, ushort* __restrict__ act) {
    int i = blockIdx.x * blockDim.x + threadIdx.x;  // one float4 per thread
    int p = i >> 8;                                  // Id/4 = 256 chunks/row
    int c = (i & 255) * 4;
    float4 g = *reinterpret_cast<const float4*>(&c1[(size_t)p * Nd + c]);
    float4 u = *reinterpret_cast<const float4*>(&c1[(size_t)p * Nd + Id + c]);
    float r0 = g.x / (1.f + __expf(-g.x)) * u.x;
    float r1 = g.y / (1.f + __expf(-g.y)) * u.y;
    float r2 = g.z / (1.f + __expf(-g.z)) * u.z;
    float r3 = g.w / (1.f + __expf(-g.w)) * u.w;
    uint2 o;
    o.x = (uint)f2bf(r0) | ((uint)f2bf(r1) << 16);
    o.y = (uint)f2bf(r2) | ((uint)f2bf(r3) << 16);
    *reinterpret_cast<uint2*>(&act[(size_t)p * Id + c]) = o;
}

// ---------------- down LoRA: cache3[p] += Bd[l,e] @ (Ad[l,e] @ act[p]) * scal ----------------
__global__ __launch_bounds__(256) void k_lora_down(
    const ushort* __restrict__ act, const float* __restrict__ Ad,
    const float* __restrict__ Bd, const float* __restrict__ scal,
    const int* __restrict__ topk_ids, const int* __restrict__ lidx,
    float* __restrict__ cache3)
{
    const int p = blockIdx.x;
    const int t = p >> 1;
    const int e = topk_ids[p];
    const int l = lidx[t];
    const float s = scal[l];
    __shared__ float tmp[Rd];

    const int tid = threadIdx.x, lane = tid & 63, wave = tid >> 6;
    const int r = wave * 4 + (lane >> 4);
    const int hl = lane & 15;
    const float* arow = Ad + (((size_t)l * Ed + e) * Rd + r) * Id;
    const ushort* xr = act + (size_t)p * Id;
    float a = 0.f;
    for (int h0 = hl * 4; h0 < Id; h0 += 64) {
        float4 av = *reinterpret_cast<const float4*>(&arow[h0]);
        ushort4 xv = *reinterpret_cast<const ushort4*>(&xr[h0]);
        a += av.x * bf2f(xv.x) + av.y * bf2f(xv.y) + av.z * bf2f(xv.z) + av.w * bf2f(xv.w);
    }
    a += __shfl_xor(a, 1); a += __shfl_xor(a, 2);
    a += __shfl_xor(a, 4); a += __shfl_xor(a, 8);
    if (hl == 0) tmp[r] = a;
    __syncthreads();

    float tl[Rd];
    #pragma unroll
    for (int q = 0; q < Rd; ++q) tl[q] = tmp[q];
    const float* Bbase = Bd + ((size_t)l * Ed + e) * Hd * Rd;
    for (int h = tid; h < Hd; h += 256) {
        const float4* br = reinterpret_cast<const float4*>(Bbase + (size_t)h * Rd);
        float4 b0 = br[0], b1 = br[1], b2 = br[2], b3 = br[3];
        float v = b0.x*tl[0] + b0.y*tl[1] + b0.z*tl[2] + b0.w*tl[3]
                + b1.x*tl[4] + b1.y*tl[5] + b1.z*tl[6] + b1.w*tl[7]
                + b2.x*tl[8] + b2.y*tl[9] + b2.z*tl[10] + b2.w*tl[11]
                + b3.x*tl[12] + b3.y*tl[13] + b3.z*tl[14] + b3.w*tl[15];
        cache3[(size_t)p * Hd + h] += v * s;
    }
}

// ---------------- finalize: out[t] = sum_k w[t,k] * cache3[t*K+k] ----------------
__global__ void k_final(const float* __restrict__ c3, const float* __restrict__ tw,
                        float* __restrict__ out) {
    int i = blockIdx.x * blockDim.x + threadIdx.x;  // one float4 per thread
    int t = i >> 8;
    int c = (i & 255) * 4;
    float w0 = tw[t * 2], w1 = tw[t * 2 + 1];
    float4 a = *reinterpret_cast<const float4*>(&c3[((size_t)t * 2) * Hd + c]);
    float4 b = *reinterpret_cast<const float4*>(&c3[((size_t)t * 2 + 1) * Hd + c]);
    float4 o;
    o.x = w0 * a.x + w1 * b.x;
    o.y = w0 * a.y + w1 * b.y;
    o.z = w0 * a.z + w1 * b.z;
    o.w = w0 * a.w + w1 * b.w;
    *reinterpret_cast<float4*>(&out[(size_t)t * Hd + c]) = o;
}

extern "C" void kernel_launch(void* const* d_in, const int* in_sizes, int n_in,
                              void* d_out, int out_size, void* d_ws, size_t ws_size,
                              hipStream_t stream) {
    const float* hid  = (const float*)d_in[0];
    const float* tw   = (const float*)d_in[1];
    const float* w13  = (const float*)d_in[2];
    const float* w2   = (const float*)d_in[3];
    const float* ga   = (const float*)d_in[4];
    const float* gb   = (const float*)d_in[5];
    const float* da   = (const float*)d_in[6];
    const float* db   = (const float*)d_in[7];
    const float* sc   = (const float*)d_in[8];
    const int*   tids = (const int*)d_in[9];
    const int*   lidx = (const int*)d_in[10];
    float* out = (float*)d_out;

    char* ws = (char*)d_ws;
    ushort* xb     = (ushort*)(ws);                       // 2 MB
    float*  cache1 = (float*)(ws + (2u << 20));           // 16 MB
    ushort* act    = (ushort*)(ws + (18u << 20));         // 4 MB
    float*  cache3 = (float*)(ws + (22u << 20));          // 8 MB
    int*    sorted = (int*)(ws + (30u << 20));            // 8 KB
    int*    offs   = (int*)(ws + (30u << 20) + TKd * 4);  // 36 B

    k_convert_x<<<(Td * Hd / 4) / 256, 256, 0, stream>>>(hid, xb);
    k_route<<<1, 1024, 0, stream>>>(tids, sorted, offs);
    k_gemm<Nd, true><<<dim3(Nd / 128, TKd / 64, Ed), 256, 0, stream>>>(xb, w13, cache1, sorted, offs);
    k_lora_gateup<<<TKd, 256, 0, stream>>>(hid, ga, gb, sc, tids, lidx, cache1);
    k_silu<<<(TKd * Id / 4) / 256, 256, 0, stream>>>(cache1, act);
    k_gemm<Hd, false><<<dim3(Hd / 128, TKd / 64, Ed), 256, 0, stream>>>(act, w2, cache3, sorted, offs);
    k_lora_down<<<TKd, 256, 0, stream>>>(act, da, db, sc, tids, lidx, cache3);
    k_final<<<(Td * Hd / 4) / 256, 256, 0, stream>>>(cache3, tw, out);
}

// Round 2
// 143.532 us; speedup vs baseline: 1.3385x; 1.3385x over previous
//
#include <hip/hip_runtime.h>
#include <stdint.h>

#define Td 1024
#define Hd 1024
#define Id 1024
#define Ed 8
#define Kd 2
#define Ld 4
#define Rd 16
#define Nd 2048
#define TKd (Td*Kd)

typedef __bf16 bf16x8 __attribute__((ext_vector_type(8)));
typedef float f32x4 __attribute__((ext_vector_type(4)));

__device__ __forceinline__ ushort f2bf(float f) {
    uint32_t u = __builtin_bit_cast(uint32_t, f);
    return (ushort)((u + 0x7fffu + ((u >> 16) & 1u)) >> 16);
}
__device__ __forceinline__ float bf2f(ushort u) {
    uint32_t x = ((uint32_t)u) << 16;
    return __builtin_bit_cast(float, x);
}

#define GLOAD_LDS16(g, l) __builtin_amdgcn_global_load_lds( \
    (const __attribute__((address_space(1))) uint32_t*)(const void*)(g), \
    (__attribute__((address_space(3))) uint32_t*)(void*)(l), 16, 0, 0)

// ---------------- convert hidden fp32 -> bf16 ----------------
__global__ void k_convert_x(const float* __restrict__ x, ushort* __restrict__ xb) {
    int i = blockIdx.x * blockDim.x + threadIdx.x;      // one float4 per thread
    float4 v = reinterpret_cast<const float4*>(x)[i];
    uint2 o;
    o.x = (uint)f2bf(v.x) | ((uint)f2bf(v.y) << 16);
    o.y = (uint)f2bf(v.z) | ((uint)f2bf(v.w) << 16);
    reinterpret_cast<uint2*>(xb)[i] = o;
}

// ---------------- convert weights fp32 -> bf16 (w13 then w2) ----------------
__global__ void k_convert_w(const float* __restrict__ w13, const float* __restrict__ w2,
                            ushort* __restrict__ w13b, ushort* __restrict__ w2b) {
    int i = blockIdx.x * blockDim.x + threadIdx.x;      // 8 floats per thread
    const float* src; ushort* dst; size_t off;
    constexpr int W13C = Ed * Nd * Hd / 8;
    if (i < W13C) { src = w13; dst = w13b; off = (size_t)i * 8; }
    else          { src = w2;  dst = w2b;  off = (size_t)(i - W13C) * 8; }
    float4 a = *reinterpret_cast<const float4*>(src + off);
    float4 b = *reinterpret_cast<const float4*>(src + off + 4);
    uint4 o;
    o.x = (uint)f2bf(a.x) | ((uint)f2bf(a.y) << 16);
    o.y = (uint)f2bf(a.z) | ((uint)f2bf(a.w) << 16);
    o.z = (uint)f2bf(b.x) | ((uint)f2bf(b.y) << 16);
    o.w = (uint)f2bf(b.z) | ((uint)f2bf(b.w) << 16);
    *reinterpret_cast<uint4*>(dst + off) = o;
}

// ---------------- route sort: bucket pairs by expert ----------------
__global__ void k_route(const int* __restrict__ topk_ids, int* __restrict__ sorted,
                        int* __restrict__ offs) {
    __shared__ int cnt[Ed];
    __shared__ int cur[Ed];
    int tid = threadIdx.x;            // 1024 threads, 2 pairs each
    if (tid < Ed) cnt[tid] = 0;
    __syncthreads();
    int e0 = topk_ids[tid];
    int e1 = topk_ids[tid + 1024];
    atomicAdd(&cnt[e0], 1);
    atomicAdd(&cnt[e1], 1);
    __syncthreads();
    if (tid == 0) {
        int s = 0;
        for (int e = 0; e < Ed; ++e) { offs[e] = s; cur[e] = s; s += cnt[e]; }
        offs[Ed] = s;
    }
    __syncthreads();
    int pos = atomicAdd(&cur[e0], 1);
    sorted[pos] = tid;
    pos = atomicAdd(&cur[e1], 1);
    sorted[pos] = tid + 1024;
}

// ---------------- grouped GEMM (m97 structure): C[p,n] = sum_k A[row(p),k]*B[e][n,k] ----------------
// A: bf16 rows [*,1024] (gathered). B: bf16 [E][NC][1024]. C: fp32 [TK][NC].
// 4 waves in 2x2 quadrants; wave owns (BM/2)x64; frags MREP x 4 of 16x16; BK=32.
template<int NC, int BM, bool ROWDIV>
__global__ __launch_bounds__(256) void k_gemm2(
    const ushort* __restrict__ Ab, const ushort* __restrict__ Bb,
    float* __restrict__ C, const int* __restrict__ sorted,
    const int* __restrict__ offs)
{
    const int e = blockIdx.z;
    const int mstart = offs[e] + blockIdx.y * BM;
    const int mend = offs[e + 1];
    if (mstart >= mend) return;
    const int n0 = blockIdx.x * 128;

    constexpr int MREP = BM / 32;
    constexpr int AROUNDS = BM / 64;

    __shared__ ushort As[BM][32];
    __shared__ ushort Bs[128][32];

    const int tid = threadIdx.x;
    const int lane = tid & 63;
    const int wave = tid >> 6;
    const int wr = wave >> 1, wc = wave & 1;

    // staging sources: chunk c -> row = c>>2, kchunk = c&3 (8 bf16 = 16B)
    const ushort* asrc[AROUNDS];
    #pragma unroll
    for (int r = 0; r < AROUNDS; ++r) {
        int c = r * 256 + tid;
        int row = c >> 2, kc = c & 3;
        int aIdx = mstart + row;
        if (aIdx > mend - 1) aIdx = mend - 1;
        int p = sorted[aIdx];
        int ar = ROWDIV ? (p >> 1) : p;
        asrc[r] = Ab + (size_t)ar * 1024 + kc * 8;
    }
    const ushort* bsrc[2];
    #pragma unroll
    for (int r = 0; r < 2; ++r) {
        int c = r * 256 + tid;
        int n = c >> 2, kc = c & 3;
        bsrc[r] = Bb + ((size_t)e * NC + n0 + n) * 1024 + kc * 8;
    }

    f32x4 acc[MREP][4] = {};
    const int fr = lane & 15;
    const int fk = (lane >> 4) * 8;

    for (int k0 = 0; k0 < 1024; k0 += 32) {
        #pragma unroll
        for (int r = 0; r < AROUNDS; ++r)
            GLOAD_LDS16(asrc[r] + k0, (char*)As + (r * 256 + wave * 64) * 16);
        #pragma unroll
        for (int r = 0; r < 2; ++r)
            GLOAD_LDS16(bsrc[r] + k0, (char*)Bs + (r * 256 + wave * 64) * 16);

        asm volatile("s_waitcnt vmcnt(0)" ::: "memory");
        __syncthreads();

        bf16x8 af[MREP], bfv[4];
        #pragma unroll
        for (int mi = 0; mi < MREP; ++mi)
            af[mi] = *reinterpret_cast<const bf16x8*>(&As[wr * (BM / 2) + mi * 16 + fr][fk]);
        #pragma unroll
        for (int ni = 0; ni < 4; ++ni)
            bfv[ni] = *reinterpret_cast<const bf16x8*>(&Bs[wc * 64 + ni * 16 + fr][fk]);
        #pragma unroll
        for (int mi = 0; mi < MREP; ++mi) {
            #pragma unroll
            for (int ni = 0; ni < 4; ++ni)
                acc[mi][ni] = __builtin_amdgcn_mfma_f32_16x16x32_bf16(
                    af[mi], bfv[ni], acc[mi][ni], 0, 0, 0);
        }

        __syncthreads();
    }

    // epilogue: D layout col=lane&15 (n-dim), row=(lane>>4)*4+j (m-dim)
    const int rb = wr * (BM / 2) + (lane >> 4) * 4;
    #pragma unroll
    for (int mi = 0; mi < MREP; ++mi) {
        #pragma unroll
        for (int j = 0; j < 4; ++j) {
            int sidx = mstart + rb + mi * 16 + j;
            if (sidx < mend) {
                int p = sorted[sidx];
                float* cr = C + (size_t)p * NC + n0 + wc * 64 + fr;
                #pragma unroll
                for (int ni = 0; ni < 4; ++ni)
                    cr[ni * 16] = acc[mi][ni][j];
            }
        }
    }
}

// ---------------- gate_up LoRA: cache1[p] += Bg[l,e] @ (Ag[l,e] @ x[t]) * scal ----------------
__global__ __launch_bounds__(256) void k_lora_gateup(
    const float* __restrict__ hid, const float* __restrict__ Ag,
    const float* __restrict__ Bg, const float* __restrict__ scal,
    const int* __restrict__ topk_ids, const int* __restrict__ lidx,
    float* __restrict__ cache1)
{
    const int p = blockIdx.x;
    const int t = p >> 1;
    const int e = topk_ids[p];
    const int l = lidx[t];
    const float s = scal[l];
    __shared__ float tmp[Rd];

    const int tid = threadIdx.x, lane = tid & 63, wave = tid >> 6;
    const int r = wave * 4 + (lane >> 4);
    const int hl = lane & 15;
    const float* arow = Ag + (((size_t)l * Ed + e) * Rd + r) * Hd;
    const float* xr = hid + (size_t)t * Hd;
    float a = 0.f;
    for (int h0 = hl * 4; h0 < Hd; h0 += 64) {
        float4 av = *reinterpret_cast<const float4*>(&arow[h0]);
        float4 xv = *reinterpret_cast<const float4*>(&xr[h0]);
        a += av.x * xv.x + av.y * xv.y + av.z * xv.z + av.w * xv.w;
    }
    a += __shfl_xor(a, 1); a += __shfl_xor(a, 2);
    a += __shfl_xor(a, 4); a += __shfl_xor(a, 8);
    if (hl == 0) tmp[r] = a;
    __syncthreads();

    float tl[Rd];
    #pragma unroll
    for (int q = 0; q < Rd; ++q) tl[q] = tmp[q];
    const float* Bbase = Bg + ((size_t)l * Ed + e) * Nd * Rd;
    for (int n = tid; n < Nd; n += 256) {
        const float4* br = reinterpret_cast<const float4*>(Bbase + (size_t)n * Rd);
        float4 b0 = br[0], b1 = br[1], b2 = br[2], b3 = br[3];
        float v = b0.x*tl[0] + b0.y*tl[1] + b0.z*tl[2] + b0.w*tl[3]
                + b1.x*tl[4] + b1.y*tl[5] + b1.z*tl[6] + b1.w*tl[7]
                + b2.x*tl[8] + b2.y*tl[9] + b2.z*tl[10] + b2.w*tl[11]
                + b3.x*tl[12] + b3.y*tl[13] + b3.z*tl[14] + b3.w*tl[15];
        cache1[(size_t)p * Nd + n] += v * s;
    }
}

// ---------------- silu_and_mul -> bf16 act ----------------
__global__ void k_silu(const float* __restrict__ c1, ushort* __restrict__ act) {
    int i = blockIdx.x * blockDim.x + threadIdx.x;  // one float4 per thread
    int p = i >> 8;                                  // Id/4 = 256 chunks/row
    int c = (i & 255) * 4;
    float4 g = *reinterpret_cast<const float4*>(&c1[(size_t)p * Nd + c]);
    float4 u = *reinterpret_cast<const float4*>(&c1[(size_t)p * Nd + Id + c]);
    float r0 = g.x / (1.f + __expf(-g.x)) * u.x;
    float r1 = g.y / (1.f + __expf(-g.y)) * u.y;
    float r2 = g.z / (1.f + __expf(-g.z)) * u.z;
    float r3 = g.w / (1.f + __expf(-g.w)) * u.w;
    uint2 o;
    o.x = (uint)f2bf(r0) | ((uint)f2bf(r1) << 16);
    o.y = (uint)f2bf(r2) | ((uint)f2bf(r3) << 16);
    *reinterpret_cast<uint2*>(&act[(size_t)p * Id + c]) = o;
}

// ---------------- down LoRA: cache3[p] += Bd[l,e] @ (Ad[l,e] @ act[p]) * scal ----------------
__global__ __launch_bounds__(256) void k_lora_down(
    const ushort* __restrict__ act, const float* __restrict__ Ad,
    const float* __restrict__ Bd, const float* __restrict__ scal,
    const int* __restrict__ topk_ids, const int* __restrict__ lidx,
    float* __restrict__ cache3)
{
    const int p = blockIdx.x;
    const int t = p >> 1;
    const int e = topk_ids[p];
    const int l = lidx[t];
    const float s = scal[l];
    __shared__ float tmp[Rd];

    const int tid = threadIdx.x, lane = tid & 63, wave = tid >> 6;
    const int r = wave * 4 + (lane >> 4);
    const int hl = lane & 15;
    const float* arow = Ad + (((size_t)l * Ed + e) * Rd + r) * Id;
    const ushort* xr = act + (size_t)p * Id;
    float a = 0.f;
    for (int h0 = hl * 4; h0 < Id; h0 += 64) {
        float4 av = *reinterpret_cast<const float4*>(&arow[h0]);
        ushort4 xv = *reinterpret_cast<const ushort4*>(&xr[h0]);
        a += av.x * bf2f(xv.x) + av.y * bf2f(xv.y) + av.z * bf2f(xv.z) + av.w * bf2f(xv.w);
    }
    a += __shfl_xor(a, 1); a += __shfl_xor(a, 2);
    a += __shfl_xor(a, 4); a += __shfl_xor(a, 8);
    if (hl == 0) tmp[r] = a;
    __syncthreads();

    float tl[Rd];
    #pragma unroll
    for (int q = 0; q < Rd; ++q) tl[q] = tmp[q];
    const float* Bbase = Bd + ((size_t)l * Ed + e) * Hd * Rd;
    for (int h = tid; h < Hd; h += 256) {
        const float4* br = reinterpret_cast<const float4*>(Bbase + (size_t)h * Rd);
        float4 b0 = br[0], b1 = br[1], b2 = br[2], b3 = br[3];
        float v = b0.x*tl[0] + b0.y*tl[1] + b0.z*tl[2] + b0.w*tl[3]
                + b1.x*tl[4] + b1.y*tl[5] + b1.z*tl[6] + b1.w*tl[7]
                + b2.x*tl[8] + b2.y*tl[9] + b2.z*tl[10] + b2.w*tl[11]
                + b3.x*tl[12] + b3.y*tl[13] + b3.z*tl[14] + b3.w*tl[15];
        cache3[(size_t)p * Hd + h] += v * s;
    }
}

// ---------------- finalize: out[t] = sum_k w[t,k] * cache3[t*K+k] ----------------
__global__ void k_final(const float* __restrict__ c3, const float* __restrict__ tw,
                        float* __restrict__ out) {
    int i = blockIdx.x * blockDim.x + threadIdx.x;  // one float4 per thread
    int t = i >> 8;
    int c = (i & 255) * 4;
    float w0 = tw[t * 2], w1 = tw[t * 2 + 1];
    float4 a = *reinterpret_cast<const float4*>(&c3[((size_t)t * 2) * Hd + c]);
    float4 b = *reinterpret_cast<const float4*>(&c3[((size_t)t * 2 + 1) * Hd + c]);
    float4 o;
    o.x = w0 * a.x + w1 * b.x;
    o.y = w0 * a.y + w1 * b.y;
    o.z = w0 * a.z + w1 * b.z;
    o.w = w0 * a.w + w1 * b.w;
    *reinterpret_cast<float4*>(&out[(size_t)t * Hd + c]) = o;
}

extern "C" void kernel_launch(void* const* d_in, const int* in_sizes, int n_in,
                              void* d_out, int out_size, void* d_ws, size_t ws_size,
                              hipStream_t stream) {
    const float* hid  = (const float*)d_in[0];
    const float* tw   = (const float*)d_in[1];
    const float* w13  = (const float*)d_in[2];
    const float* w2   = (const float*)d_in[3];
    const float* ga   = (const float*)d_in[4];
    const float* gb   = (const float*)d_in[5];
    const float* da   = (const float*)d_in[6];
    const float* db   = (const float*)d_in[7];
    const float* sc   = (const float*)d_in[8];
    const int*   tids = (const int*)d_in[9];
    const int*   lidx = (const int*)d_in[10];
    float* out = (float*)d_out;

    char* ws = (char*)d_ws;
    ushort* xb     = (ushort*)(ws);                        // 2 MB
    ushort* w13b   = (ushort*)(ws + (2ull  << 20));        // 32 MB
    ushort* w2b    = (ushort*)(ws + (34ull << 20));        // 16 MB
    float*  cache1 = (float*)(ws + (50ull << 20));         // 16 MB
    ushort* act    = (ushort*)(ws + (66ull << 20));        // 4 MB
    float*  cache3 = (float*)(ws + (70ull << 20));         // 8 MB
    int*    sorted = (int*)(ws + (78ull << 20));           // 8 KB
    int*    offs   = (int*)(ws + (78ull << 20) + TKd * 4); // 36 B

    k_convert_x<<<(Td * Hd / 4) / 256, 256, 0, stream>>>(hid, xb);
    k_convert_w<<<(Ed * Nd * Hd + Ed * Hd * Id) / 8 / 256, 256, 0, stream>>>(w13, w2, w13b, w2b);
    k_route<<<1, 1024, 0, stream>>>(tids, sorted, offs);
    k_gemm2<Nd, 128, true><<<dim3(Nd / 128, TKd / 128, Ed), 256, 0, stream>>>(xb, w13b, cache1, sorted, offs);
    k_lora_gateup<<<TKd, 256, 0, stream>>>(hid, ga, gb, sc, tids, lidx, cache1);
    k_silu<<<(TKd * Id / 4) / 256, 256, 0, stream>>>(cache1, act);
    k_gemm2<Hd, 64, false><<<dim3(Hd / 128, TKd / 64, Ed), 256, 0, stream>>>(act, w2b, cache3, sorted, offs);
    k_lora_down<<<TKd, 256, 0, stream>>>(act, da, db, sc, tids, lidx, cache3);
    k_final<<<(Td * Hd / 4) / 256, 256, 0, stream>>>(cache3, tw, out);
}